// Round 3
// baseline (3077.405 us; speedup 1.0000x reference)
//
#include <hip/hip_runtime.h>

#define NN 50000
#define PM 4
#define EE 500000
#define INF_ 128
#define NH 8
#define FF 32
#define HF 256
#define HS 128
#define BG 128
#define OUTC 2

#define NB2 98        // buckets per path: dst>>9 (512 nodes/bucket)
#define BCAP 6144     // bucket capacity (mean 5102, sigma ~71 -> 14 sigma slack)
#define CHUNK 8192    // edges per workgroup in bucket pass

typedef __attribute__((ext_vector_type(8))) short bf16x8;
typedef __attribute__((ext_vector_type(4))) float f32x4;

__device__ __forceinline__ float b2f(unsigned short x) {
  unsigned u = ((unsigned)x) << 16;
  return __builtin_bit_cast(float, u);
}
__device__ __forceinline__ unsigned short f2b(float f) {
  unsigned u = __builtin_bit_cast(unsigned, f);
  u += 0x7fff + ((u >> 16) & 1);   // RNE
  return (unsigned short)(u >> 16);
}

// ---------------------------------------------------------------------------
__global__ void f2b_kernel(const float* __restrict__ src, unsigned short* __restrict__ dst, int n4) {
  int t = blockIdx.x * 256 + threadIdx.x;
  if (t >= n4) return;
  float4 v = *(const float4*)(src + (size_t)t * 4);
  ushort4 o;
  o.x = f2b(v.x); o.y = f2b(v.y); o.z = f2b(v.z); o.w = f2b(v.w);
  *(ushort4*)(dst + (size_t)t * 4) = o;
}

__global__ void twg_kernel(const float* __restrict__ Wg, unsigned short* __restrict__ Wt) {
  int t = blockIdx.x * 256 + threadIdx.x;
  if (t >= PM * HF * INF_) return;
  int p = t >> 15, rem = t & 32767;
  int n = rem >> 7, k = rem & 127;
  Wt[(size_t)p * 32768 + n * 128 + k] = f2b(Wg[(size_t)p * 32768 + k * 256 + n]);
}

__global__ void tw1_kernel(const float* __restrict__ W1, unsigned short* __restrict__ Wt) {
  int t = blockIdx.x * 256 + threadIdx.x;
  if (t >= HF * HS) return;
  int n = t >> 8, k = t & 255;
  Wt[n * 256 + k] = f2b(W1[k * 128 + n]);
}

__global__ void fold_kernel(const float* __restrict__ Wg, const float* __restrict__ al,
                            const float* __restrict__ ar, float* __restrict__ wl,
                            float* __restrict__ wr) {
  int t = blockIdx.x * 256 + threadIdx.x;
  if (t >= PM * INF_ * NH) return;
  int p = t >> 10, rem = t & 1023;
  int k = rem >> 3, h = rem & 7;
  const float* wrow = Wg + (size_t)p * 32768 + k * 256 + h * 32;
  const float* alp = al + p * 256 + h * 32;
  const float* arp = ar + p * 256 + h * 32;
  float sl = 0.f, sr = 0.f;
  #pragma unroll
  for (int f = 0; f < 32; f++) { sl += wrow[f] * alp[f]; sr += wrow[f] * arp[f]; }
  wl[t] = sl; wr[t] = sr;
}

__global__ __launch_bounds__(256) void elr_kernel(
    const float* __restrict__ h, const float* __restrict__ wl,
    const float* __restrict__ wr, float* __restrict__ el, float* __restrict__ er, int N) {
  __shared__ float wls[128 * 8], wrs[128 * 8];
  for (int i = threadIdx.x; i < 1024; i += 256) { wls[i] = wl[i]; wrs[i] = wr[i]; }
  __syncthreads();
  int n = blockIdx.x * 256 + threadIdx.x;
  if (n >= N) return;
  float accl[8] = {}, accr[8] = {};
  for (int k4 = 0; k4 < 32; k4++) {
    float4 hv = *(const float4*)(h + (size_t)n * 128 + k4 * 4);
    float vv[4] = {hv.x, hv.y, hv.z, hv.w};
    #pragma unroll
    for (int j = 0; j < 4; j++) {
      float v = vv[j];
      int k = k4 * 4 + j;
      #pragma unroll
      for (int hh = 0; hh < 8; hh++) {
        accl[hh] += v * wls[k * 8 + hh];
        accr[hh] += v * wrs[k * 8 + hh];
      }
    }
  }
  *(float4*)(el + (size_t)n * 8)     = make_float4(accl[0], accl[1], accl[2], accl[3]);
  *(float4*)(el + (size_t)n * 8 + 4) = make_float4(accl[4], accl[5], accl[6], accl[7]);
  *(float4*)(er + (size_t)n * 8)     = make_float4(accr[0], accr[1], accr[2], accr[3]);
  *(float4*)(er + (size_t)n * 8 + 4) = make_float4(accr[4], accr[5], accr[6], accr[7]);
}

// ---------------------------------------------------------------------------
// GEMM1: hp_b[M,256] = h_b[M,128] @ W, MFMA bf16
__global__ __launch_bounds__(256) void gemm1_kernel(
    const unsigned short* __restrict__ hA, const unsigned short* __restrict__ Bt,
    unsigned short* __restrict__ Cb, int M) {
  __shared__ unsigned short As[64 * 128];
  __shared__ unsigned short Bs[128 * 128];
  int tid = threadIdx.x;
  int row0 = blockIdx.x * 64, col0 = blockIdx.y * 128;
  #pragma unroll
  for (int i = 0; i < 4; i++) {
    int c = i * 256 + tid;
    int row = c >> 4, g = c & 15;
    int grow = row0 + row;
    uint4 v = make_uint4(0, 0, 0, 0);
    if (grow < M) v = *(const uint4*)(hA + (size_t)grow * 128 + g * 8);
    *(uint4*)&As[row * 128 + ((g ^ (row & 15)) << 3)] = v;
  }
  #pragma unroll
  for (int i = 0; i < 8; i++) {
    int c = i * 256 + tid;
    int row = c >> 4, g = c & 15;
    uint4 v = *(const uint4*)(Bt + (size_t)(col0 + row) * 128 + g * 8);
    *(uint4*)&Bs[row * 128 + ((g ^ (row & 15)) << 3)] = v;
  }
  __syncthreads();
  int wave = tid >> 6, lane = tid & 63;
  int ln = lane & 15, quad = lane >> 4;
  int mbase = (wave >> 1) * 32, nbase = (wave & 1) * 64;
  f32x4 acc[2][4] = {};
  #pragma unroll
  for (int ks = 0; ks < 4; ks++) {
    int g = ks * 4 + quad;
    bf16x8 a[2], b[4];
    #pragma unroll
    for (int mi = 0; mi < 2; mi++) {
      int r = mbase + mi * 16 + ln;
      a[mi] = *(const bf16x8*)&As[r * 128 + ((g ^ ln) << 3)];
    }
    #pragma unroll
    for (int ni = 0; ni < 4; ni++) {
      int r = nbase + ni * 16 + ln;
      b[ni] = *(const bf16x8*)&Bs[r * 128 + ((g ^ ln) << 3)];
    }
    #pragma unroll
    for (int mi = 0; mi < 2; mi++)
      #pragma unroll
      for (int ni = 0; ni < 4; ni++)
        acc[mi][ni] = __builtin_amdgcn_mfma_f32_16x16x32_bf16(a[mi], b[ni], acc[mi][ni], 0, 0, 0);
  }
  #pragma unroll
  for (int mi = 0; mi < 2; mi++) {
    int gm0 = row0 + mbase + mi * 16 + quad * 4;
    #pragma unroll
    for (int ni = 0; ni < 4; ni++) {
      int gn = col0 + nbase + ni * 16 + ln;
      #pragma unroll
      for (int r = 0; r < 4; r++) {
        int gm = gm0 + r;
        if (gm < M) Cb[(size_t)gm * 256 + gn] = f2b(acc[mi][ni][r]);
      }
    }
  }
}

// ---------------------------------------------------------------------------
// GEMM2 + semantic epilogue
__global__ __launch_bounds__(256) void gemm2_kernel(
    const unsigned short* __restrict__ A, const unsigned short* __restrict__ Bt,
    const float* __restrict__ b1, const float* __restrict__ W2,
    float* __restrict__ wsum, int M) {
  __shared__ unsigned short As[64 * 128];
  __shared__ unsigned short Bs[128 * 128];
  int tid = threadIdx.x;
  int row0 = blockIdx.x * 64;
  int wave = tid >> 6, lane = tid & 63;
  int ln = lane & 15, quad = lane >> 4;
  int mbase = (wave >> 1) * 32, nbase = (wave & 1) * 64;
  f32x4 acc[2][4] = {};
  for (int kc = 0; kc < 2; kc++) {
    #pragma unroll
    for (int i = 0; i < 4; i++) {
      int c = i * 256 + tid;
      int row = c >> 4, g = c & 15;
      int grow = row0 + row;
      uint4 v = make_uint4(0, 0, 0, 0);
      if (grow < M) v = *(const uint4*)(A + (size_t)grow * 256 + kc * 128 + g * 8);
      *(uint4*)&As[row * 128 + ((g ^ (row & 15)) << 3)] = v;
    }
    #pragma unroll
    for (int i = 0; i < 8; i++) {
      int c = i * 256 + tid;
      int row = c >> 4, g = c & 15;
      uint4 v = *(const uint4*)(Bt + (size_t)row * 256 + kc * 128 + g * 8);
      *(uint4*)&Bs[row * 128 + ((g ^ (row & 15)) << 3)] = v;
    }
    __syncthreads();
    #pragma unroll
    for (int ks = 0; ks < 4; ks++) {
      int g = ks * 4 + quad;
      bf16x8 a[2], b[4];
      #pragma unroll
      for (int mi = 0; mi < 2; mi++) {
        int r = mbase + mi * 16 + ln;
        a[mi] = *(const bf16x8*)&As[r * 128 + ((g ^ ln) << 3)];
      }
      #pragma unroll
      for (int ni = 0; ni < 4; ni++) {
        int r = nbase + ni * 16 + ln;
        b[ni] = *(const bf16x8*)&Bs[r * 128 + ((g ^ ln) << 3)];
      }
      #pragma unroll
      for (int mi = 0; mi < 2; mi++)
        #pragma unroll
        for (int ni = 0; ni < 4; ni++)
          acc[mi][ni] = __builtin_amdgcn_mfma_f32_16x16x32_bf16(a[mi], b[ni], acc[mi][ni], 0, 0, 0);
    }
    __syncthreads();
  }
  float b1v[4], w2v[4];
  #pragma unroll
  for (int ni = 0; ni < 4; ni++) {
    int col = nbase + ni * 16 + ln;
    b1v[ni] = b1[col]; w2v[ni] = W2[col];
  }
  float s = 0.f;
  #pragma unroll
  for (int mi = 0; mi < 2; mi++) {
    int gm0 = row0 + mbase + mi * 16 + quad * 4;
    #pragma unroll
    for (int r = 0; r < 4; r++) {
      if (gm0 + r < M) {
        #pragma unroll
        for (int ni = 0; ni < 4; ni++)
          s += tanhf(acc[mi][ni][r] + b1v[ni]) * w2v[ni];
      }
    }
  }
  #pragma unroll
  for (int o = 32; o > 0; o >>= 1) s += __shfl_down(s, o);
  if (lane == 0) atomicAdd(wsum, s);
}

// ---------------------------------------------------------------------------
// Pass 1: bin edges by dst>>9 into per-path buckets. Per-wave 8-entry LDS
// staging buffers -> 32 B contiguous global appends (kills the 64B-line
// write amplification of a direct scatter).
__global__ __launch_bounds__(256) void bucket_kernel(
    const int* __restrict__ src, const int* __restrict__ dst,
    unsigned* __restrict__ bdata, int* __restrict__ gcnt) {
  __shared__ unsigned buf[4][NB2][8];
  __shared__ int bcnt[4][NB2];
  int p = blockIdx.y;
  int wv = threadIdx.x >> 6, lane = threadIdx.x & 63;
  for (int i = threadIdx.x; i < 4 * NB2; i += 256) ((int*)bcnt)[i] = 0;
  __syncthreads();
  const int* sp = src + (size_t)p * EE;
  const int* dp = dst + (size_t)p * EE;
  int base = blockIdx.x * CHUNK + wv * (CHUNK / 4);
  int wend = min(base + CHUNK / 4, EE);
  for (int e0 = base; e0 < wend; e0 += 64) {
    int e = e0 + lane;
    bool pend = e < wend;
    unsigned pk = 0; int bk = 0;
    if (pend) {
      int s = sp[e], d = dp[e];
      pk = ((unsigned)d << 16) | (unsigned)s;
      bk = d >> 9;
    }
    while (__any(pend)) {
      int slot = -1;
      if (pend) slot = atomicAdd(&bcnt[wv][bk], 1);
      if (pend && slot < 8) buf[wv][bk][slot] = pk;
      if (pend && slot == 7) {   // this lane flushes 8 entries
        int gb = atomicAdd(&gcnt[p * NB2 + bk], 8);
        if (gb + 8 <= BCAP) {
          unsigned* dp2 = bdata + ((size_t)(p * NB2 + bk)) * BCAP + gb;
          #pragma unroll
          for (int j = 0; j < 8; j++) dp2[j] = buf[wv][bk][j];
        }
        bcnt[wv][bk] = 0;
      }
      pend = pend && (slot >= 8);
    }
  }
  // drain partial buffers (per-wave, no cross-wave deps)
  for (int k = lane; k < NB2; k += 64) {
    int c = bcnt[wv][k];
    if (c > 0) {
      int gb = atomicAdd(&gcnt[p * NB2 + k], c);
      unsigned* dp2 = bdata + ((size_t)(p * NB2 + k)) * BCAP;
      for (int j = 0; j < c; j++)
        if (gb + j < BCAP) dp2[gb + j] = buf[wv][k][j];
    }
  }
}

// ---------------------------------------------------------------------------
// Pass 2: per (path,bucket) workgroup: local CSR build in LDS, then GAT
// aggregation (wave per dst node): out = (sum w*hp)/(sum w), +bias, ELU.
__global__ __launch_bounds__(256) void csragg_kernel(
    const unsigned* __restrict__ bdata, const int* __restrict__ gcnt,
    const unsigned short* __restrict__ hp_b, const float* __restrict__ el,
    const float* __restrict__ er, const float* __restrict__ bias,
    unsigned short* __restrict__ emb_b) {
  __shared__ unsigned ebuf[BCAP];
  __shared__ unsigned short csrc[BCAP];
  __shared__ int degc[512];
  __shared__ int off[513];
  __shared__ int tmp[256];
  int p = blockIdx.y, b = blockIdx.x;
  int tid = threadIdx.x;
  int cnt = min(gcnt[p * NB2 + b], BCAP);
  const unsigned* bp = bdata + ((size_t)(p * NB2 + b)) * BCAP;
  for (int i = tid; i < cnt; i += 256) ebuf[i] = bp[i];
  degc[tid] = 0; degc[256 + tid] = 0;
  __syncthreads();
  for (int i = tid; i < cnt; i += 256)
    atomicAdd(&degc[(ebuf[i] >> 16) & 511], 1);
  __syncthreads();
  // exclusive scan of degc[0..511] -> off
  int d0 = degc[2 * tid], d1 = degc[2 * tid + 1];
  tmp[tid] = d0 + d1;
  __syncthreads();
  for (int o = 1; o < 256; o <<= 1) {
    int v = (tid >= o) ? tmp[tid - o] : 0;
    __syncthreads();
    tmp[tid] += v;
    __syncthreads();
  }
  int bse = tmp[tid] - d0 - d1;
  off[2 * tid] = bse; off[2 * tid + 1] = bse + d0;
  if (tid == 255) off[512] = tmp[255];
  __syncthreads();
  degc[tid] = 0; degc[256 + tid] = 0;   // reuse as cur
  __syncthreads();
  for (int i = tid; i < cnt; i += 256) {
    unsigned pk = ebuf[i];
    int dl = (pk >> 16) & 511;
    int slot = off[dl] + atomicAdd(&degc[dl], 1);
    csrc[slot] = (unsigned short)(pk & 0xffff);
  }
  __syncthreads();
  // aggregation
  int wv = tid >> 6, lane = tid & 63;
  int hh = lane >> 3;
  float4 bv = *(const float4*)(bias + lane * 4);
  for (int dl = wv; dl < 512; dl += 4) {
    int n = b * 512 + dl;
    if (n >= NN) break;
    int e0 = off[dl], e1 = off[dl + 1];
    float erh = er[n * NH + hh];
    float den = 0.f, a0 = 0.f, a1 = 0.f, a2 = 0.f, a3 = 0.f;
    for (int e = e0; e < e1; e++) {
      int s = csrc[e];
      float x = el[s * NH + hh] + erh;
      x = (x > 0.f) ? x : 0.2f * x;
      float w = expf(x);
      den += w;
      ushort4 hv = *(const ushort4*)(hp_b + (size_t)s * HF + lane * 4);
      a0 += w * b2f(hv.x); a1 += w * b2f(hv.y);
      a2 += w * b2f(hv.z); a3 += w * b2f(hv.w);
    }
    float inv = (den > 0.f) ? 1.f / den : 0.f;
    float o0 = a0 * inv + bv.x, o1 = a1 * inv + bv.y;
    float o2 = a2 * inv + bv.z, o3 = a3 * inv + bv.w;
    o0 = (o0 > 0.f) ? o0 : expf(o0) - 1.f;
    o1 = (o1 > 0.f) ? o1 : expf(o1) - 1.f;
    o2 = (o2 > 0.f) ? o2 : expf(o2) - 1.f;
    o3 = (o3 > 0.f) ? o3 : expf(o3) - 1.f;
    ushort4 ov;
    ov.x = f2b(o0); ov.y = f2b(o1); ov.z = f2b(o2); ov.w = f2b(o3);
    *(ushort4*)(emb_b + (size_t)n * HF + lane * 4) = ov;
  }
}

// ---------------------------------------------------------------------------
__global__ void cntg_kernel(const int* __restrict__ gid, float* __restrict__ cnt, int N) {
  int t = blockIdx.x * 256 + threadIdx.x;
  if (t < N) atomicAdd(&cnt[gid[t]], 1.0f);
}

__global__ __launch_bounds__(256) void pool_kernel(
    const unsigned short* __restrict__ emb, const int* __restrict__ gid,
    float* __restrict__ pool, int N) {
  __shared__ float acc[BG * 64];
  int f0 = blockIdx.x * 64;
  int lane = threadIdx.x & 63, grp = threadIdx.x >> 6;
  for (int i = threadIdx.x; i < BG * 64; i += 256) acc[i] = 0.f;
  __syncthreads();
  int nb = (int)gridDim.y;
  int chunk = (N + nb - 1) / nb;
  int start = blockIdx.y * chunk;
  int end = min(start + chunk, N);
  int glen = (end - start + 3) >> 2;
  int gstart = start + grp * glen;
  int gend = min(gstart + glen, end);
  for (int n = gstart; n < gend; n++) {
    int g = gid[n];
    float v = b2f(emb[(size_t)n * HF + f0 + lane]);
    atomicAdd(&acc[g * 64 + lane], v);
  }
  __syncthreads();
  for (int i = threadIdx.x; i < BG * 64; i += 256) {
    float v = acc[i];
    if (v != 0.f) {
      int g = i >> 6, f = i & 63;
      atomicAdd(&pool[g * HF + f0 + f], v);
    }
  }
}

__global__ __launch_bounds__(256) void final_kernel(
    const float* __restrict__ pool, const float* __restrict__ wsum,
    const float* __restrict__ cnt, const float* __restrict__ clsW,
    const float* __restrict__ clsb, float* __restrict__ out, int N) {
  int b = blockIdx.x;
  int f = threadIdx.x;
  float wm[PM];
  float mx = -1e30f;
  #pragma unroll
  for (int p = 0; p < PM; p++) { wm[p] = wsum[p] / (float)N; mx = fmaxf(mx, wm[p]); }
  float es = 0.f, e[PM];
  #pragma unroll
  for (int p = 0; p < PM; p++) { e[p] = expf(wm[p] - mx); es += e[p]; }
  float c = fmaxf(cnt[b], 1.f);
  float v = 0.f;
  #pragma unroll
  for (int p = 0; p < PM; p++)
    v += (e[p] / es) * pool[((size_t)p * BG + b) * HF + f];
  v /= c;
  out[256 + (size_t)b * HF + f] = v;
  __shared__ float sm[256];
  sm[f] = v * clsW[f * 2 + 0];
  __syncthreads();
  for (int st = 128; st > 0; st >>= 1) {
    if (f < st) sm[f] += sm[f + st];
    __syncthreads();
  }
  float l0 = sm[0];
  __syncthreads();
  sm[f] = v * clsW[f * 2 + 1];
  __syncthreads();
  for (int st = 128; st > 0; st >>= 1) {
    if (f < st) sm[f] += sm[f + st];
    __syncthreads();
  }
  if (f == 0) {
    out[b * 2 + 0] = l0 + clsb[0];
    out[b * 2 + 1] = sm[0] + clsb[1];
  }
}

// ---------------------------------------------------------------------------
extern "C" void kernel_launch(void* const* d_in, const int* in_sizes, int n_in,
                              void* d_out, int out_size, void* d_ws, size_t ws_size,
                              hipStream_t stream) {
  const float* h      = (const float*)d_in[0];
  const float* Wg     = (const float*)d_in[1];
  const float* attn_l = (const float*)d_in[2];
  const float* attn_r = (const float*)d_in[3];
  const float* gatb   = (const float*)d_in[4];
  const float* semW1  = (const float*)d_in[5];
  const float* semb1  = (const float*)d_in[6];
  const float* semW2  = (const float*)d_in[7];
  const float* clsW   = (const float*)d_in[8];
  const float* clsb   = (const float*)d_in[9];
  const int*   src    = (const int*)d_in[10];
  const int*   dst    = (const int*)d_in[11];
  const int*   gid    = (const int*)d_in[12];
  float* out = (float*)d_out;

  char* ws = (char*)d_ws;
  size_t o = 0;
  auto alloc = [&](size_t bytes) { size_t r = o; o += (bytes + 255) & ~(size_t)255; return r; };
  unsigned short* h_b   = (unsigned short*)(ws + alloc((size_t)NN * INF_ * 2));
  unsigned short* hp_b  = (unsigned short*)(ws + alloc((size_t)NN * HF * 2));
  unsigned short* emb_b = (unsigned short*)(ws + alloc((size_t)NN * HF * 2));
  unsigned short* Wb_t  = (unsigned short*)(ws + alloc((size_t)PM * HF * INF_ * 2));
  unsigned short* W1_t  = (unsigned short*)(ws + alloc((size_t)HS * HF * 2));
  float* wl    = (float*)(ws + alloc((size_t)PM * INF_ * NH * 4));
  float* wr    = (float*)(ws + alloc((size_t)PM * INF_ * NH * 4));
  float* el    = (float*)(ws + alloc((size_t)NN * NH * 4));
  float* er    = (float*)(ws + alloc((size_t)NN * NH * 4));
  unsigned* bdata = (unsigned*)(ws + alloc((size_t)PM * NB2 * BCAP * 4));
  int*   gcnt  = (int*)(ws + alloc((size_t)PM * NB2 * 4));
  float* pool  = (float*)(ws + alloc((size_t)PM * BG * HF * 4));
  float* wsum  = (float*)(ws + alloc(PM * 4));
  float* cnt   = (float*)(ws + alloc(BG * 4));

  hipMemsetAsync(gcnt, 0, (size_t)PM * NB2 * 4, stream);
  hipMemsetAsync(pool, 0, (size_t)PM * BG * HF * 4, stream);
  hipMemsetAsync(wsum, 0, PM * 4, stream);
  hipMemsetAsync(cnt, 0, BG * 4, stream);

  f2b_kernel<<<((NN * INF_ / 4) + 255) / 256, 256, 0, stream>>>(h, h_b, NN * INF_ / 4);
  twg_kernel<<<(PM * HF * INF_ + 255) / 256, 256, 0, stream>>>(Wg, Wb_t);
  tw1_kernel<<<(HF * HS + 255) / 256, 256, 0, stream>>>(semW1, W1_t);
  fold_kernel<<<(PM * INF_ * NH + 255) / 256, 256, 0, stream>>>(Wg, attn_l, attn_r, wl, wr);
  cntg_kernel<<<(NN + 255) / 256, 256, 0, stream>>>(gid, cnt, NN);

  bucket_kernel<<<dim3((EE + CHUNK - 1) / CHUNK, PM), 256, 0, stream>>>(src, dst, bdata, gcnt);

  for (int p = 0; p < PM; p++) {
    gemm1_kernel<<<dim3((NN + 63) / 64, 2), 256, 0, stream>>>(
        h_b, Wb_t + (size_t)p * HF * INF_, hp_b, NN);
    elr_kernel<<<(NN + 255) / 256, 256, 0, stream>>>(
        h, wl + (size_t)p * INF_ * NH, wr + (size_t)p * INF_ * NH, el, er, NN);
    csragg_kernel<<<dim3(NB2, 1), 256, 0, stream>>>(
        bdata + (size_t)p * NB2 * BCAP, gcnt + p * NB2, hp_b, el, er,
        gatb + (size_t)p * HF, emb_b);
    gemm2_kernel<<<(NN + 63) / 64, 256, 0, stream>>>(
        emb_b, W1_t, semb1, semW2, wsum + p, NN);
    pool_kernel<<<dim3(4, 64), 256, 0, stream>>>(emb_b, gid, pool + (size_t)p * BG * HF, NN);
  }

  final_kernel<<<BG, 256, 0, stream>>>(pool, wsum, cnt, clsW, clsb, out, NN);
}

// Round 4
// 1194.003 us; speedup vs baseline: 2.5774x; 2.5774x over previous
//
#include <hip/hip_runtime.h>

#define NN 50000
#define PM 4
#define EE 500000
#define INF_ 128
#define NH 8
#define FF 32
#define HF 256
#define HS 128
#define BG 128
#define OUTC 2

#define NB2 98        // buckets per path: dst>>9 (512 nodes/bucket)
#define BCAP 6144     // bucket capacity (mean 5102, sd ~71 -> 14 sigma slack)
#define CHUNK 8192    // edges per workgroup in bucket pass

typedef __attribute__((ext_vector_type(8))) short bf16x8;
typedef __attribute__((ext_vector_type(4))) float f32x4;

__device__ __forceinline__ float b2f(unsigned short x) {
  unsigned u = ((unsigned)x) << 16;
  return __builtin_bit_cast(float, u);
}
__device__ __forceinline__ unsigned short f2b(float f) {
  unsigned u = __builtin_bit_cast(unsigned, f);
  u += 0x7fff + ((u >> 16) & 1);   // RNE
  return (unsigned short)(u >> 16);
}

// ---------------------------------------------------------------------------
__global__ void f2b_kernel(const float* __restrict__ src, unsigned short* __restrict__ dst, int n4) {
  int t = blockIdx.x * 256 + threadIdx.x;
  if (t >= n4) return;
  float4 v = *(const float4*)(src + (size_t)t * 4);
  ushort4 o;
  o.x = f2b(v.x); o.y = f2b(v.y); o.z = f2b(v.z); o.w = f2b(v.w);
  *(ushort4*)(dst + (size_t)t * 4) = o;
}

__global__ void twg_kernel(const float* __restrict__ Wg, unsigned short* __restrict__ Wt) {
  int t = blockIdx.x * 256 + threadIdx.x;
  if (t >= PM * HF * INF_) return;
  int p = t >> 15, rem = t & 32767;
  int n = rem >> 7, k = rem & 127;
  Wt[(size_t)p * 32768 + n * 128 + k] = f2b(Wg[(size_t)p * 32768 + k * 256 + n]);
}

__global__ void tw1_kernel(const float* __restrict__ W1, unsigned short* __restrict__ Wt) {
  int t = blockIdx.x * 256 + threadIdx.x;
  if (t >= HF * HS) return;
  int n = t >> 8, k = t & 255;
  Wt[n * 256 + k] = f2b(W1[k * 128 + n]);
}

__global__ void fold_kernel(const float* __restrict__ Wg, const float* __restrict__ al,
                            const float* __restrict__ ar, float* __restrict__ wl,
                            float* __restrict__ wr) {
  int t = blockIdx.x * 256 + threadIdx.x;
  if (t >= PM * INF_ * NH) return;
  int p = t >> 10, rem = t & 1023;
  int k = rem >> 3, h = rem & 7;
  const float* wrow = Wg + (size_t)p * 32768 + k * 256 + h * 32;
  const float* alp = al + p * 256 + h * 32;
  const float* arp = ar + p * 256 + h * 32;
  float sl = 0.f, sr = 0.f;
  #pragma unroll
  for (int f = 0; f < 32; f++) { sl += wrow[f] * alp[f]; sr += wrow[f] * arp[f]; }
  wl[t] = sl; wr[t] = sr;
}

__global__ __launch_bounds__(256) void elr_kernel(
    const float* __restrict__ h, const float* __restrict__ wl,
    const float* __restrict__ wr, float* __restrict__ el, float* __restrict__ er, int N) {
  __shared__ float wls[128 * 8], wrs[128 * 8];
  for (int i = threadIdx.x; i < 1024; i += 256) { wls[i] = wl[i]; wrs[i] = wr[i]; }
  __syncthreads();
  int n = blockIdx.x * 256 + threadIdx.x;
  if (n >= N) return;
  float accl[8] = {}, accr[8] = {};
  for (int k4 = 0; k4 < 32; k4++) {
    float4 hv = *(const float4*)(h + (size_t)n * 128 + k4 * 4);
    float vv[4] = {hv.x, hv.y, hv.z, hv.w};
    #pragma unroll
    for (int j = 0; j < 4; j++) {
      float v = vv[j];
      int k = k4 * 4 + j;
      #pragma unroll
      for (int hh = 0; hh < 8; hh++) {
        accl[hh] += v * wls[k * 8 + hh];
        accr[hh] += v * wrs[k * 8 + hh];
      }
    }
  }
  *(float4*)(el + (size_t)n * 8)     = make_float4(accl[0], accl[1], accl[2], accl[3]);
  *(float4*)(el + (size_t)n * 8 + 4) = make_float4(accl[4], accl[5], accl[6], accl[7]);
  *(float4*)(er + (size_t)n * 8)     = make_float4(accr[0], accr[1], accr[2], accr[3]);
  *(float4*)(er + (size_t)n * 8 + 4) = make_float4(accr[4], accr[5], accr[6], accr[7]);
}

// ---------------------------------------------------------------------------
// GEMM1: hp_b[M,256] = h_b[M,128] @ W, MFMA bf16
__global__ __launch_bounds__(256) void gemm1_kernel(
    const unsigned short* __restrict__ hA, const unsigned short* __restrict__ Bt,
    unsigned short* __restrict__ Cb, int M) {
  __shared__ unsigned short As[64 * 128];
  __shared__ unsigned short Bs[128 * 128];
  int tid = threadIdx.x;
  int row0 = blockIdx.x * 64, col0 = blockIdx.y * 128;
  #pragma unroll
  for (int i = 0; i < 4; i++) {
    int c = i * 256 + tid;
    int row = c >> 4, g = c & 15;
    int grow = row0 + row;
    uint4 v = make_uint4(0, 0, 0, 0);
    if (grow < M) v = *(const uint4*)(hA + (size_t)grow * 128 + g * 8);
    *(uint4*)&As[row * 128 + ((g ^ (row & 15)) << 3)] = v;
  }
  #pragma unroll
  for (int i = 0; i < 8; i++) {
    int c = i * 256 + tid;
    int row = c >> 4, g = c & 15;
    uint4 v = *(const uint4*)(Bt + (size_t)(col0 + row) * 128 + g * 8);
    *(uint4*)&Bs[row * 128 + ((g ^ (row & 15)) << 3)] = v;
  }
  __syncthreads();
  int wave = tid >> 6, lane = tid & 63;
  int ln = lane & 15, quad = lane >> 4;
  int mbase = (wave >> 1) * 32, nbase = (wave & 1) * 64;
  f32x4 acc[2][4] = {};
  #pragma unroll
  for (int ks = 0; ks < 4; ks++) {
    int g = ks * 4 + quad;
    bf16x8 a[2], b[4];
    #pragma unroll
    for (int mi = 0; mi < 2; mi++) {
      int r = mbase + mi * 16 + ln;
      a[mi] = *(const bf16x8*)&As[r * 128 + ((g ^ ln) << 3)];
    }
    #pragma unroll
    for (int ni = 0; ni < 4; ni++) {
      int r = nbase + ni * 16 + ln;
      b[ni] = *(const bf16x8*)&Bs[r * 128 + ((g ^ ln) << 3)];
    }
    #pragma unroll
    for (int mi = 0; mi < 2; mi++)
      #pragma unroll
      for (int ni = 0; ni < 4; ni++)
        acc[mi][ni] = __builtin_amdgcn_mfma_f32_16x16x32_bf16(a[mi], b[ni], acc[mi][ni], 0, 0, 0);
  }
  #pragma unroll
  for (int mi = 0; mi < 2; mi++) {
    int gm0 = row0 + mbase + mi * 16 + quad * 4;
    #pragma unroll
    for (int ni = 0; ni < 4; ni++) {
      int gn = col0 + nbase + ni * 16 + ln;
      #pragma unroll
      for (int r = 0; r < 4; r++) {
        int gm = gm0 + r;
        if (gm < M) Cb[(size_t)gm * 256 + gn] = f2b(acc[mi][ni][r]);
      }
    }
  }
}

// ---------------------------------------------------------------------------
// GEMM2 + semantic epilogue
__global__ __launch_bounds__(256) void gemm2_kernel(
    const unsigned short* __restrict__ A, const unsigned short* __restrict__ Bt,
    const float* __restrict__ b1, const float* __restrict__ W2,
    float* __restrict__ wsum, int M) {
  __shared__ unsigned short As[64 * 128];
  __shared__ unsigned short Bs[128 * 128];
  int tid = threadIdx.x;
  int row0 = blockIdx.x * 64;
  int wave = tid >> 6, lane = tid & 63;
  int ln = lane & 15, quad = lane >> 4;
  int mbase = (wave >> 1) * 32, nbase = (wave & 1) * 64;
  f32x4 acc[2][4] = {};
  for (int kc = 0; kc < 2; kc++) {
    #pragma unroll
    for (int i = 0; i < 4; i++) {
      int c = i * 256 + tid;
      int row = c >> 4, g = c & 15;
      int grow = row0 + row;
      uint4 v = make_uint4(0, 0, 0, 0);
      if (grow < M) v = *(const uint4*)(A + (size_t)grow * 256 + kc * 128 + g * 8);
      *(uint4*)&As[row * 128 + ((g ^ (row & 15)) << 3)] = v;
    }
    #pragma unroll
    for (int i = 0; i < 8; i++) {
      int c = i * 256 + tid;
      int row = c >> 4, g = c & 15;
      uint4 v = *(const uint4*)(Bt + (size_t)row * 256 + kc * 128 + g * 8);
      *(uint4*)&Bs[row * 128 + ((g ^ (row & 15)) << 3)] = v;
    }
    __syncthreads();
    #pragma unroll
    for (int ks = 0; ks < 4; ks++) {
      int g = ks * 4 + quad;
      bf16x8 a[2], b[4];
      #pragma unroll
      for (int mi = 0; mi < 2; mi++) {
        int r = mbase + mi * 16 + ln;
        a[mi] = *(const bf16x8*)&As[r * 128 + ((g ^ ln) << 3)];
      }
      #pragma unroll
      for (int ni = 0; ni < 4; ni++) {
        int r = nbase + ni * 16 + ln;
        b[ni] = *(const bf16x8*)&Bs[r * 128 + ((g ^ ln) << 3)];
      }
      #pragma unroll
      for (int mi = 0; mi < 2; mi++)
        #pragma unroll
        for (int ni = 0; ni < 4; ni++)
          acc[mi][ni] = __builtin_amdgcn_mfma_f32_16x16x32_bf16(a[mi], b[ni], acc[mi][ni], 0, 0, 0);
    }
    __syncthreads();
  }
  float b1v[4], w2v[4];
  #pragma unroll
  for (int ni = 0; ni < 4; ni++) {
    int col = nbase + ni * 16 + ln;
    b1v[ni] = b1[col]; w2v[ni] = W2[col];
  }
  float s = 0.f;
  #pragma unroll
  for (int mi = 0; mi < 2; mi++) {
    int gm0 = row0 + mbase + mi * 16 + quad * 4;
    #pragma unroll
    for (int r = 0; r < 4; r++) {
      if (gm0 + r < M) {
        #pragma unroll
        for (int ni = 0; ni < 4; ni++)
          s += tanhf(acc[mi][ni][r] + b1v[ni]) * w2v[ni];
      }
    }
  }
  #pragma unroll
  for (int o = 32; o > 0; o >>= 1) s += __shfl_down(s, o);
  if (lane == 0) atomicAdd(wsum, s);
}

// ---------------------------------------------------------------------------
// Pass 1: bin edges by dst>>9 into per-path buckets (per-wave 8-entry LDS
// staging -> 32 B contiguous global appends; avoids 64B-line scatter amp).
__global__ __launch_bounds__(256) void bucket_kernel(
    const int* __restrict__ src, const int* __restrict__ dst,
    unsigned* __restrict__ bdata, int* __restrict__ gcnt) {
  __shared__ unsigned buf[4][NB2][8];
  __shared__ int bcnt[4][NB2];
  int p = blockIdx.y;
  int wv = threadIdx.x >> 6, lane = threadIdx.x & 63;
  for (int i = threadIdx.x; i < 4 * NB2; i += 256) ((int*)bcnt)[i] = 0;
  __syncthreads();
  const int* sp = src + (size_t)p * EE;
  const int* dp = dst + (size_t)p * EE;
  int base = blockIdx.x * CHUNK + wv * (CHUNK / 4);
  int wend = min(base + CHUNK / 4, EE);
  for (int e0 = base; e0 < wend; e0 += 64) {
    int e = e0 + lane;
    bool pend = e < wend;
    unsigned pk = 0; int bk = 0;
    if (pend) {
      int s = sp[e], d = dp[e];
      pk = ((unsigned)d << 16) | (unsigned)s;
      bk = d >> 9;
    }
    while (__any(pend)) {
      int slot = -1;
      if (pend) slot = atomicAdd(&bcnt[wv][bk], 1);
      if (pend && slot < 8) buf[wv][bk][slot] = pk;
      if (pend && slot == 7) {
        int gb = atomicAdd(&gcnt[p * NB2 + bk], 8);
        if (gb + 8 <= BCAP) {
          unsigned* dp2 = bdata + ((size_t)(p * NB2 + bk)) * BCAP + gb;
          #pragma unroll
          for (int j = 0; j < 8; j++) dp2[j] = buf[wv][bk][j];
        }
        bcnt[wv][bk] = 0;
      }
      pend = pend && (slot >= 8);
    }
  }
  for (int k = lane; k < NB2; k += 64) {
    int c = bcnt[wv][k];
    if (c > 0) {
      int gb = atomicAdd(&gcnt[p * NB2 + k], c);
      unsigned* dp2 = bdata + ((size_t)(p * NB2 + k)) * BCAP;
      for (int j = 0; j < c; j++)
        if (gb + j < BCAP) dp2[gb + j] = buf[wv][k][j];
    }
  }
}

// per-path exclusive prefix of bucket counts (tiny)
__global__ void bprefix_kernel(const int* __restrict__ gcnt, int* __restrict__ bbase) {
  int p = threadIdx.x;
  if (p < PM) {
    int s = 0;
    for (int b = 0; b < NB2; b++) {
      bbase[p * (NB2 + 1) + b] = s;
      s += min(gcnt[p * NB2 + b], BCAP);
    }
    bbase[p * (NB2 + 1) + NB2] = s;
  }
}

// Pass 2: per (bucket,path): build 512-node local CSR in LDS, write global
// off[] + csr[] (ushort src) in the bucket's contiguous segment (coalesced).
__global__ __launch_bounds__(256) void csrify_kernel(
    const unsigned* __restrict__ bdata, const int* __restrict__ gcnt,
    const int* __restrict__ bbase, int* __restrict__ off,
    unsigned short* __restrict__ csr) {
  __shared__ unsigned ebuf[BCAP];
  __shared__ int degc[512];
  __shared__ int loff[513];
  __shared__ int tmp[256];
  int b = blockIdx.x, p = blockIdx.y;
  int tid = threadIdx.x;
  int cnt = min(gcnt[p * NB2 + b], BCAP);
  const unsigned* bp = bdata + ((size_t)(p * NB2 + b)) * BCAP;
  for (int i = tid; i < cnt; i += 256) ebuf[i] = bp[i];
  degc[tid] = 0; degc[256 + tid] = 0;
  __syncthreads();
  for (int i = tid; i < cnt; i += 256)
    atomicAdd(&degc[(ebuf[i] >> 16) & 511], 1);
  __syncthreads();
  int d0 = degc[2 * tid], d1 = degc[2 * tid + 1];
  tmp[tid] = d0 + d1;
  __syncthreads();
  for (int o = 1; o < 256; o <<= 1) {
    int v = (tid >= o) ? tmp[tid - o] : 0;
    __syncthreads();
    tmp[tid] += v;
    __syncthreads();
  }
  int bse = tmp[tid] - d0 - d1;
  loff[2 * tid] = bse; loff[2 * tid + 1] = bse + d0;
  if (tid == 255) loff[512] = tmp[255];
  __syncthreads();
  int base = bbase[p * (NB2 + 1) + b];
  for (int dl = tid; dl < 512; dl += 256) {
    int n = b * 512 + dl;
    if (n <= NN) off[(size_t)p * (NN + 1) + n] = base + loff[dl];
  }
  // off[NN] handled by the bucket containing dl where b*512+dl==NN (loff==cnt)
  degc[tid] = 0; degc[256 + tid] = 0;
  __syncthreads();
  for (int i = tid; i < cnt; i += 256) {
    unsigned pk = ebuf[i];
    int dl = (pk >> 16) & 511;
    int slot = loff[dl] + atomicAdd(&degc[dl], 1);
    csr[(size_t)p * EE + base + slot] = (unsigned short)(pk & 0xffff);
  }
}

// ---------------------------------------------------------------------------
// Aggregation: one wave per dst node: out = (sum w*hp)/(sum w), +bias, ELU.
__global__ __launch_bounds__(256) void agg_kernel(
    const unsigned short* __restrict__ hp_b, const float* __restrict__ el,
    const float* __restrict__ er, const unsigned short* __restrict__ csr,
    const int* __restrict__ off, const float* __restrict__ bias,
    unsigned short* __restrict__ emb_b, int N) {
  int n = blockIdx.x * 4 + (threadIdx.x >> 6);
  if (n >= N) return;
  int lane = threadIdx.x & 63;
  int h = lane >> 3;
  int e0 = off[n], e1 = off[n + 1];
  float erh = er[n * NH + h];
  float den = 0.f, a0 = 0.f, a1 = 0.f, a2 = 0.f, a3 = 0.f;
  for (int e = e0; e < e1; e++) {
    int s = csr[e];
    float x = el[s * NH + h] + erh;
    x = (x > 0.f) ? x : 0.2f * x;
    float w = expf(x);
    den += w;
    ushort4 hv = *(const ushort4*)(hp_b + (size_t)s * HF + lane * 4);
    a0 += w * b2f(hv.x); a1 += w * b2f(hv.y);
    a2 += w * b2f(hv.z); a3 += w * b2f(hv.w);
  }
  float inv = (den > 0.f) ? 1.f / den : 0.f;
  float4 bv = *(const float4*)(bias + lane * 4);
  float o0 = a0 * inv + bv.x, o1 = a1 * inv + bv.y;
  float o2 = a2 * inv + bv.z, o3 = a3 * inv + bv.w;
  o0 = (o0 > 0.f) ? o0 : expf(o0) - 1.f;
  o1 = (o1 > 0.f) ? o1 : expf(o1) - 1.f;
  o2 = (o2 > 0.f) ? o2 : expf(o2) - 1.f;
  o3 = (o3 > 0.f) ? o3 : expf(o3) - 1.f;
  ushort4 ov;
  ov.x = f2b(o0); ov.y = f2b(o1); ov.z = f2b(o2); ov.w = f2b(o3);
  *(ushort4*)(emb_b + (size_t)n * HF + lane * 4) = ov;
}

// ---------------------------------------------------------------------------
__global__ void cntg_kernel(const int* __restrict__ gid, float* __restrict__ cnt, int N) {
  int t = blockIdx.x * 256 + threadIdx.x;
  if (t < N) atomicAdd(&cnt[gid[t]], 1.0f);
}

__global__ __launch_bounds__(256) void pool_kernel(
    const unsigned short* __restrict__ emb, const int* __restrict__ gid,
    float* __restrict__ pool, int N) {
  __shared__ float acc[BG * 64];
  int f0 = blockIdx.x * 64;
  int lane = threadIdx.x & 63, grp = threadIdx.x >> 6;
  for (int i = threadIdx.x; i < BG * 64; i += 256) acc[i] = 0.f;
  __syncthreads();
  int nb = (int)gridDim.y;
  int chunk = (N + nb - 1) / nb;
  int start = blockIdx.y * chunk;
  int end = min(start + chunk, N);
  int glen = (end - start + 3) >> 2;
  int gstart = start + grp * glen;
  int gend = min(gstart + glen, end);
  for (int n = gstart; n < gend; n++) {
    int g = gid[n];
    float v = b2f(emb[(size_t)n * HF + f0 + lane]);
    atomicAdd(&acc[g * 64 + lane], v);
  }
  __syncthreads();
  for (int i = threadIdx.x; i < BG * 64; i += 256) {
    float v = acc[i];
    if (v != 0.f) {
      int g = i >> 6, f = i & 63;
      atomicAdd(&pool[g * HF + f0 + f], v);
    }
  }
}

__global__ __launch_bounds__(256) void final_kernel(
    const float* __restrict__ pool, const float* __restrict__ wsum,
    const float* __restrict__ cnt, const float* __restrict__ clsW,
    const float* __restrict__ clsb, float* __restrict__ out, int N) {
  int b = blockIdx.x;
  int f = threadIdx.x;
  float wm[PM];
  float mx = -1e30f;
  #pragma unroll
  for (int p = 0; p < PM; p++) { wm[p] = wsum[p] / (float)N; mx = fmaxf(mx, wm[p]); }
  float es = 0.f, e[PM];
  #pragma unroll
  for (int p = 0; p < PM; p++) { e[p] = expf(wm[p] - mx); es += e[p]; }
  float c = fmaxf(cnt[b], 1.f);
  float v = 0.f;
  #pragma unroll
  for (int p = 0; p < PM; p++)
    v += (e[p] / es) * pool[((size_t)p * BG + b) * HF + f];
  v /= c;
  out[256 + (size_t)b * HF + f] = v;
  __shared__ float sm[256];
  sm[f] = v * clsW[f * 2 + 0];
  __syncthreads();
  for (int st = 128; st > 0; st >>= 1) {
    if (f < st) sm[f] += sm[f + st];
    __syncthreads();
  }
  float l0 = sm[0];
  __syncthreads();
  sm[f] = v * clsW[f * 2 + 1];
  __syncthreads();
  for (int st = 128; st > 0; st >>= 1) {
    if (f < st) sm[f] += sm[f + st];
    __syncthreads();
  }
  if (f == 0) {
    out[b * 2 + 0] = l0 + clsb[0];
    out[b * 2 + 1] = sm[0] + clsb[1];
  }
}

// ---------------------------------------------------------------------------
extern "C" void kernel_launch(void* const* d_in, const int* in_sizes, int n_in,
                              void* d_out, int out_size, void* d_ws, size_t ws_size,
                              hipStream_t stream) {
  const float* h      = (const float*)d_in[0];
  const float* Wg     = (const float*)d_in[1];
  const float* attn_l = (const float*)d_in[2];
  const float* attn_r = (const float*)d_in[3];
  const float* gatb   = (const float*)d_in[4];
  const float* semW1  = (const float*)d_in[5];
  const float* semb1  = (const float*)d_in[6];
  const float* semW2  = (const float*)d_in[7];
  const float* clsW   = (const float*)d_in[8];
  const float* clsb   = (const float*)d_in[9];
  const int*   src    = (const int*)d_in[10];
  const int*   dst    = (const int*)d_in[11];
  const int*   gid    = (const int*)d_in[12];
  float* out = (float*)d_out;

  char* ws = (char*)d_ws;
  size_t o = 0;
  auto alloc = [&](size_t bytes) { size_t r = o; o += (bytes + 255) & ~(size_t)255; return r; };
  unsigned short* h_b   = (unsigned short*)(ws + alloc((size_t)NN * INF_ * 2));
  unsigned short* hp_b  = (unsigned short*)(ws + alloc((size_t)NN * HF * 2));
  unsigned short* emb_b = (unsigned short*)(ws + alloc((size_t)NN * HF * 2));
  unsigned short* Wb_t  = (unsigned short*)(ws + alloc((size_t)PM * HF * INF_ * 2));
  unsigned short* W1_t  = (unsigned short*)(ws + alloc((size_t)HS * HF * 2));
  float* wl    = (float*)(ws + alloc((size_t)PM * INF_ * NH * 4));
  float* wr    = (float*)(ws + alloc((size_t)PM * INF_ * NH * 4));
  float* el    = (float*)(ws + alloc((size_t)NN * NH * 4));
  float* er    = (float*)(ws + alloc((size_t)NN * NH * 4));
  unsigned* bdata = (unsigned*)(ws + alloc((size_t)PM * NB2 * BCAP * 4));
  int*   gcnt  = (int*)(ws + alloc((size_t)PM * NB2 * 4));
  int*   bbase = (int*)(ws + alloc((size_t)PM * (NB2 + 1) * 4));
  int*   off   = (int*)(ws + alloc((size_t)PM * (NN + 1) * 4));
  unsigned short* csr = (unsigned short*)(ws + alloc((size_t)PM * EE * 2));
  float* pool  = (float*)(ws + alloc((size_t)PM * BG * HF * 4));
  float* wsum  = (float*)(ws + alloc(PM * 4));
  float* cnt   = (float*)(ws + alloc(BG * 4));

  hipMemsetAsync(gcnt, 0, (size_t)PM * NB2 * 4, stream);
  hipMemsetAsync(pool, 0, (size_t)PM * BG * HF * 4, stream);
  hipMemsetAsync(wsum, 0, PM * 4, stream);
  hipMemsetAsync(cnt, 0, BG * 4, stream);

  f2b_kernel<<<((NN * INF_ / 4) + 255) / 256, 256, 0, stream>>>(h, h_b, NN * INF_ / 4);
  twg_kernel<<<(PM * HF * INF_ + 255) / 256, 256, 0, stream>>>(Wg, Wb_t);
  tw1_kernel<<<(HF * HS + 255) / 256, 256, 0, stream>>>(semW1, W1_t);
  fold_kernel<<<(PM * INF_ * NH + 255) / 256, 256, 0, stream>>>(Wg, attn_l, attn_r, wl, wr);
  cntg_kernel<<<(NN + 255) / 256, 256, 0, stream>>>(gid, cnt, NN);

  bucket_kernel<<<dim3((EE + CHUNK - 1) / CHUNK, PM), 256, 0, stream>>>(src, dst, bdata, gcnt);
  bprefix_kernel<<<1, 64, 0, stream>>>(gcnt, bbase);
  csrify_kernel<<<dim3(NB2, PM), 256, 0, stream>>>(bdata, gcnt, bbase, off, csr);

  for (int p = 0; p < PM; p++) {
    gemm1_kernel<<<dim3((NN + 63) / 64, 2), 256, 0, stream>>>(
        h_b, Wb_t + (size_t)p * HF * INF_, hp_b, NN);
    elr_kernel<<<(NN + 255) / 256, 256, 0, stream>>>(
        h, wl + (size_t)p * INF_ * NH, wr + (size_t)p * INF_ * NH, el, er, NN);
    agg_kernel<<<(NN + 3) / 4, 256, 0, stream>>>(
        hp_b, el, er, csr + (size_t)p * EE, off + (size_t)p * (NN + 1),
        gatb + (size_t)p * HF, emb_b, NN);
    gemm2_kernel<<<(NN + 63) / 64, 256, 0, stream>>>(
        emb_b, W1_t, semb1, semW2, wsum + p, NN);
    pool_kernel<<<dim3(4, 64), 256, 0, stream>>>(emb_b, gid, pool + (size_t)p * BG * HF, NN);
  }

  final_kernel<<<BG, 256, 0, stream>>>(pool, wsum, cnt, clsW, clsb, out, NN);
}

// Round 5
// 920.475 us; speedup vs baseline: 3.3433x; 1.2972x over previous
//
#include <hip/hip_runtime.h>

#define NN 50000
#define PM 4
#define EE 500000
#define INF_ 128
#define NH 8
#define FF 32
#define HF 256
#define HS 128
#define BG 128
#define OUTC 2

#define NB2 98        // buckets per path: dst>>9 (512 nodes/bucket)
#define BCAP 6144     // bucket capacity (mean 5102, sd ~71 -> 14 sigma slack)
#define BCH 4096      // edges per workgroup in bucket pass

typedef __attribute__((ext_vector_type(8))) short bf16x8;
typedef __attribute__((ext_vector_type(4))) float f32x4;

__device__ __forceinline__ float b2f(unsigned short x) {
  unsigned u = ((unsigned)x) << 16;
  return __builtin_bit_cast(float, u);
}
__device__ __forceinline__ unsigned short f2b(float f) {
  unsigned u = __builtin_bit_cast(unsigned, f);
  u += 0x7fff + ((u >> 16) & 1);   // RNE
  return (unsigned short)(u >> 16);
}

// ---------------------------------------------------------------------------
// prep: zero pool/gcnt/wsum + h->bf16 + Wg transpose->bf16 + W1 transpose->bf16
//       + fold attn into per-k weights. One dispatch, sections by blockIdx.x.
// ---------------------------------------------------------------------------
__global__ __launch_bounds__(256) void prep_kernel(
    const float* __restrict__ h, const float* __restrict__ Wg,
    const float* __restrict__ W1, const float* __restrict__ al,
    const float* __restrict__ ar,
    unsigned short* __restrict__ h_b, unsigned short* __restrict__ Wb_t,
    unsigned short* __restrict__ W1_t, float* __restrict__ wl,
    float* __restrict__ wr, float* __restrict__ pool,
    int* __restrict__ gcnt, float* __restrict__ wsum) {
  int b = blockIdx.x;
  int tid = threadIdx.x;
  if (b < 128) {               // zero pool: 131072 floats
    *(float4*)(pool + b * 1024 + tid * 4) = make_float4(0.f, 0.f, 0.f, 0.f);
    return;
  }
  b -= 128;
  if (b < 1) {                 // zero gcnt + wsum
    for (int i = tid; i < PM * NB2; i += 256) gcnt[i] = 0;
    if (tid < PM) wsum[tid] = 0.f;
    return;
  }
  b -= 1;
  if (b < 6250) {              // h -> bf16 (float4 granular)
    int t = b * 256 + tid;     // t < 1.6M exactly
    float4 v = *(const float4*)(h + (size_t)t * 4);
    ushort4 o;
    o.x = f2b(v.x); o.y = f2b(v.y); o.z = f2b(v.z); o.w = f2b(v.w);
    *(ushort4*)(h_b + (size_t)t * 4) = o;
    return;
  }
  b -= 6250;
  if (b < 512) {               // Wg [P][128k][256n] -> [P][256n][128k] bf16
    int t = b * 256 + tid;
    int p = t >> 15, rem = t & 32767;
    int n = rem >> 7, k = rem & 127;
    Wb_t[(size_t)p * 32768 + n * 128 + k] = f2b(Wg[(size_t)p * 32768 + k * 256 + n]);
    return;
  }
  b -= 512;
  if (b < 128) {               // W1 [256k][128n] -> [128n][256k] bf16
    int t = b * 256 + tid;
    int n = t >> 8, k = t & 255;
    W1_t[n * 256 + k] = f2b(W1[k * 128 + n]);
    return;
  }
  b -= 128;
  {                            // fold: wl/wr[p][k][h]
    int t = b * 256 + tid;     // t < 4096
    int p = t >> 10, rem = t & 1023;
    int k = rem >> 3, hh = rem & 7;
    const float* wrow = Wg + (size_t)p * 32768 + k * 256 + hh * 32;
    const float* alp = al + p * 256 + hh * 32;
    const float* arp = ar + p * 256 + hh * 32;
    float sl = 0.f, sr = 0.f;
    #pragma unroll
    for (int f = 0; f < 32; f++) { sl += wrow[f] * alp[f]; sr += wrow[f] * arp[f]; }
    wl[t] = sl; wr[t] = sr;
  }
}

// ---------------------------------------------------------------------------
// bucket: per-block histogram -> one global atomic per (block,bucket) to
// reserve a contiguous segment -> LDS-cursor scatter. No retry loops.
// ---------------------------------------------------------------------------
__global__ __launch_bounds__(256) void bucket_kernel(
    const int* __restrict__ src, const int* __restrict__ dst,
    unsigned* __restrict__ bdata, int* __restrict__ gcnt) {
  __shared__ unsigned ed[BCH];
  __shared__ int hist[NB2], gbase[NB2], cur[NB2];
  int p = blockIdx.y;
  int e0 = blockIdx.x * BCH;
  int n = min(BCH, EE - e0);
  int tid = threadIdx.x;
  if (tid < NB2) hist[tid] = 0;
  __syncthreads();
  const int* sp = src + (size_t)p * EE + e0;
  const int* dp = dst + (size_t)p * EE + e0;
  for (int i = tid; i < n; i += 256) {
    int s = sp[i], d = dp[i];
    ed[i] = ((unsigned)d << 16) | (unsigned)s;
    atomicAdd(&hist[d >> 9], 1);
  }
  __syncthreads();
  if (tid < NB2) {
    gbase[tid] = atomicAdd(&gcnt[p * NB2 + tid], hist[tid]);
    cur[tid] = 0;
  }
  __syncthreads();
  for (int i = tid; i < n; i += 256) {
    unsigned pk = ed[i];
    int bk = pk >> 25;           // (dst>>9)
    int slot = gbase[bk] + atomicAdd(&cur[bk], 1);
    if (slot < BCAP)
      bdata[((size_t)(p * NB2 + bk)) * BCAP + slot] = pk;
  }
}

// ---------------------------------------------------------------------------
// csrify: per (bucket,path): 512-node local CSR in LDS, write global off[]
// + csr[] (ushort src). Base = running sum of bucket counts (LDS).
// ---------------------------------------------------------------------------
__global__ __launch_bounds__(256) void csrify_kernel(
    const unsigned* __restrict__ bdata, const int* __restrict__ gcnt,
    int* __restrict__ off, unsigned short* __restrict__ csr) {
  __shared__ unsigned ebuf[BCAP];
  __shared__ int gc[NB2];
  __shared__ int degc[512];
  __shared__ int loff[513];
  __shared__ int tmp[256];
  __shared__ int base_s;
  int b = blockIdx.x, p = blockIdx.y;
  int tid = threadIdx.x;
  if (tid < NB2) gc[tid] = min(gcnt[p * NB2 + tid], BCAP);
  __syncthreads();
  if (tid == 0) {
    int s = 0;
    for (int i = 0; i < b; i++) s += gc[i];
    base_s = s;
  }
  int cnt = gc[b];
  const unsigned* bp = bdata + ((size_t)(p * NB2 + b)) * BCAP;
  for (int i = tid; i < cnt; i += 256) ebuf[i] = bp[i];
  degc[tid] = 0; degc[256 + tid] = 0;
  __syncthreads();
  for (int i = tid; i < cnt; i += 256)
    atomicAdd(&degc[(ebuf[i] >> 16) & 511], 1);
  __syncthreads();
  int d0 = degc[2 * tid], d1 = degc[2 * tid + 1];
  tmp[tid] = d0 + d1;
  __syncthreads();
  for (int o = 1; o < 256; o <<= 1) {
    int v = (tid >= o) ? tmp[tid - o] : 0;
    __syncthreads();
    tmp[tid] += v;
    __syncthreads();
  }
  int bse = tmp[tid] - d0 - d1;
  loff[2 * tid] = bse; loff[2 * tid + 1] = bse + d0;
  if (tid == 255) loff[512] = tmp[255];
  __syncthreads();
  int base = base_s;
  for (int dl = tid; dl < 512; dl += 256) {
    int n = b * 512 + dl;
    if (n <= NN) off[(size_t)p * (NN + 1) + n] = base + loff[dl];
  }
  degc[tid] = 0; degc[256 + tid] = 0;   // reuse as cursors
  __syncthreads();
  for (int i = tid; i < cnt; i += 256) {
    unsigned pk = ebuf[i];
    int dl = (pk >> 16) & 511;
    int slot = loff[dl] + atomicAdd(&degc[dl], 1);
    csr[(size_t)p * EE + base + slot] = (unsigned short)(pk & 0xffff);
  }
}

// ---------------------------------------------------------------------------
// GEMM1: hp_b[p][M,256] = h_b[M,128] @ W[p], MFMA bf16. p = p0 + blockIdx.z.
// ---------------------------------------------------------------------------
__global__ __launch_bounds__(256) void gemm1_kernel(
    const unsigned short* __restrict__ hA, const unsigned short* __restrict__ Bt,
    unsigned short* __restrict__ Cb, int M, int p0, size_t cstride) {
  __shared__ unsigned short As[64 * 128];
  __shared__ unsigned short Bs[128 * 128];
  int tid = threadIdx.x;
  int pl = blockIdx.z;
  const unsigned short* Bp = Bt + (size_t)(p0 + pl) * 32768;
  unsigned short* Cp = Cb + (size_t)pl * cstride;
  int row0 = blockIdx.x * 64, col0 = blockIdx.y * 128;
  #pragma unroll
  for (int i = 0; i < 4; i++) {
    int c = i * 256 + tid;
    int row = c >> 4, g = c & 15;
    int grow = row0 + row;
    uint4 v = make_uint4(0, 0, 0, 0);
    if (grow < M) v = *(const uint4*)(hA + (size_t)grow * 128 + g * 8);
    *(uint4*)&As[row * 128 + ((g ^ (row & 15)) << 3)] = v;
  }
  #pragma unroll
  for (int i = 0; i < 8; i++) {
    int c = i * 256 + tid;
    int row = c >> 4, g = c & 15;
    uint4 v = *(const uint4*)(Bp + (size_t)(col0 + row) * 128 + g * 8);
    *(uint4*)&Bs[row * 128 + ((g ^ (row & 15)) << 3)] = v;
  }
  __syncthreads();
  int wave = tid >> 6, lane = tid & 63;
  int ln = lane & 15, quad = lane >> 4;
  int mbase = (wave >> 1) * 32, nbase = (wave & 1) * 64;
  f32x4 acc[2][4] = {};
  #pragma unroll
  for (int ks = 0; ks < 4; ks++) {
    int g = ks * 4 + quad;
    bf16x8 a[2], bb[4];
    #pragma unroll
    for (int mi = 0; mi < 2; mi++) {
      int r = mbase + mi * 16 + ln;
      a[mi] = *(const bf16x8*)&As[r * 128 + ((g ^ ln) << 3)];
    }
    #pragma unroll
    for (int ni = 0; ni < 4; ni++) {
      int r = nbase + ni * 16 + ln;
      bb[ni] = *(const bf16x8*)&Bs[r * 128 + ((g ^ ln) << 3)];
    }
    #pragma unroll
    for (int mi = 0; mi < 2; mi++)
      #pragma unroll
      for (int ni = 0; ni < 4; ni++)
        acc[mi][ni] = __builtin_amdgcn_mfma_f32_16x16x32_bf16(a[mi], bb[ni], acc[mi][ni], 0, 0, 0);
  }
  #pragma unroll
  for (int mi = 0; mi < 2; mi++) {
    int gm0 = row0 + mbase + mi * 16 + quad * 4;
    #pragma unroll
    for (int ni = 0; ni < 4; ni++) {
      int gn = col0 + nbase + ni * 16 + ln;
      #pragma unroll
      for (int r = 0; r < 4; r++) {
        int gm = gm0 + r;
        if (gm < M) Cp[(size_t)gm * 256 + gn] = f2b(acc[mi][ni][r]);
      }
    }
  }
}

// ---------------------------------------------------------------------------
// elr: el/er = h @ folded weights (fp32 exact). p = p0 + blockIdx.y.
// ---------------------------------------------------------------------------
__global__ __launch_bounds__(256) void elr_kernel(
    const float* __restrict__ h, const float* __restrict__ wl,
    const float* __restrict__ wr, float* __restrict__ el,
    float* __restrict__ er, int N, int p0, size_t estride) {
  __shared__ float wls[128 * 8], wrs[128 * 8];
  int pl = blockIdx.y;
  const float* wlp = wl + (size_t)(p0 + pl) * 1024;
  const float* wrp = wr + (size_t)(p0 + pl) * 1024;
  float* elp = el + (size_t)pl * estride;
  float* erp = er + (size_t)pl * estride;
  for (int i = threadIdx.x; i < 1024; i += 256) { wls[i] = wlp[i]; wrs[i] = wrp[i]; }
  __syncthreads();
  int n = blockIdx.x * 256 + threadIdx.x;
  if (n >= N) return;
  float accl[8] = {}, accr[8] = {};
  for (int k4 = 0; k4 < 32; k4++) {
    float4 hv = *(const float4*)(h + (size_t)n * 128 + k4 * 4);
    float vv[4] = {hv.x, hv.y, hv.z, hv.w};
    #pragma unroll
    for (int j = 0; j < 4; j++) {
      float v = vv[j];
      int k = k4 * 4 + j;
      #pragma unroll
      for (int hh = 0; hh < 8; hh++) {
        accl[hh] += v * wls[k * 8 + hh];
        accr[hh] += v * wrs[k * 8 + hh];
      }
    }
  }
  *(float4*)(elp + (size_t)n * 8)     = make_float4(accl[0], accl[1], accl[2], accl[3]);
  *(float4*)(elp + (size_t)n * 8 + 4) = make_float4(accl[4], accl[5], accl[6], accl[7]);
  *(float4*)(erp + (size_t)n * 8)     = make_float4(accr[0], accr[1], accr[2], accr[3]);
  *(float4*)(erp + (size_t)n * 8 + 4) = make_float4(accr[4], accr[5], accr[6], accr[7]);
}

// ---------------------------------------------------------------------------
// agg: one wave per dst node: out = (sum w*hp)/(sum w), +bias, ELU -> bf16.
// ---------------------------------------------------------------------------
__global__ __launch_bounds__(256) void agg_kernel(
    const unsigned short* __restrict__ hp_b, const float* __restrict__ el,
    const float* __restrict__ er, const unsigned short* __restrict__ csr,
    const int* __restrict__ off, const float* __restrict__ bias,
    unsigned short* __restrict__ emb_b, int N, int p0,
    size_t hstride, size_t estride, size_t embstride) {
  int pl = blockIdx.y;
  int p = p0 + pl;
  const unsigned short* hp = hp_b + (size_t)pl * hstride;
  const float* elp = el + (size_t)pl * estride;
  const float* erp = er + (size_t)pl * estride;
  const unsigned short* csrp = csr + (size_t)p * EE;
  const int* offp = off + (size_t)p * (NN + 1);
  const float* bp = bias + (size_t)p * HF;
  unsigned short* embp = emb_b + (size_t)pl * embstride;
  int n = blockIdx.x * 4 + (threadIdx.x >> 6);
  if (n >= N) return;
  int lane = threadIdx.x & 63;
  int h = lane >> 3;
  int e0 = offp[n], e1 = offp[n + 1];
  float erh = erp[n * NH + h];
  float den = 0.f, a0 = 0.f, a1 = 0.f, a2 = 0.f, a3 = 0.f;
  for (int e = e0; e < e1; e++) {
    int s = csrp[e];
    float x = elp[s * NH + h] + erh;
    x = (x > 0.f) ? x : 0.2f * x;
    float w = expf(x);
    den += w;
    ushort4 hv = *(const ushort4*)(hp + (size_t)s * HF + lane * 4);
    a0 += w * b2f(hv.x); a1 += w * b2f(hv.y);
    a2 += w * b2f(hv.z); a3 += w * b2f(hv.w);
  }
  float inv = (den > 0.f) ? 1.f / den : 0.f;
  float4 bv = *(const float4*)(bp + lane * 4);
  float o0 = a0 * inv + bv.x, o1 = a1 * inv + bv.y;
  float o2 = a2 * inv + bv.z, o3 = a3 * inv + bv.w;
  o0 = (o0 > 0.f) ? o0 : expf(o0) - 1.f;
  o1 = (o1 > 0.f) ? o1 : expf(o1) - 1.f;
  o2 = (o2 > 0.f) ? o2 : expf(o2) - 1.f;
  o3 = (o3 > 0.f) ? o3 : expf(o3) - 1.f;
  ushort4 ov;
  ov.x = f2b(o0); ov.y = f2b(o1); ov.z = f2b(o2); ov.w = f2b(o3);
  *(ushort4*)(embp + (size_t)n * HF + lane * 4) = ov;
}

// ---------------------------------------------------------------------------
// GEMM2 + semantic epilogue: wsum[p] += sum tanh(emb@W1+b1).W2
// ---------------------------------------------------------------------------
__global__ __launch_bounds__(256) void gemm2_kernel(
    const unsigned short* __restrict__ A, const unsigned short* __restrict__ Bt,
    const float* __restrict__ b1, const float* __restrict__ W2,
    float* __restrict__ wsum, int M, int p0, size_t astride) {
  __shared__ unsigned short As[64 * 128];
  __shared__ unsigned short Bs[128 * 128];
  int tid = threadIdx.x;
  int pl = blockIdx.y;
  const unsigned short* Ap = A + (size_t)pl * astride;
  int row0 = blockIdx.x * 64;
  int wave = tid >> 6, lane = tid & 63;
  int ln = lane & 15, quad = lane >> 4;
  int mbase = (wave >> 1) * 32, nbase = (wave & 1) * 64;
  f32x4 acc[2][4] = {};
  for (int kc = 0; kc < 2; kc++) {
    #pragma unroll
    for (int i = 0; i < 4; i++) {
      int c = i * 256 + tid;
      int row = c >> 4, g = c & 15;
      int grow = row0 + row;
      uint4 v = make_uint4(0, 0, 0, 0);
      if (grow < M) v = *(const uint4*)(Ap + (size_t)grow * 256 + kc * 128 + g * 8);
      *(uint4*)&As[row * 128 + ((g ^ (row & 15)) << 3)] = v;
    }
    #pragma unroll
    for (int i = 0; i < 8; i++) {
      int c = i * 256 + tid;
      int row = c >> 4, g = c & 15;
      uint4 v = *(const uint4*)(Bt + (size_t)row * 256 + kc * 128 + g * 8);
      *(uint4*)&Bs[row * 128 + ((g ^ (row & 15)) << 3)] = v;
    }
    __syncthreads();
    #pragma unroll
    for (int ks = 0; ks < 4; ks++) {
      int g = ks * 4 + quad;
      bf16x8 a[2], bb[4];
      #pragma unroll
      for (int mi = 0; mi < 2; mi++) {
        int r = mbase + mi * 16 + ln;
        a[mi] = *(const bf16x8*)&As[r * 128 + ((g ^ ln) << 3)];
      }
      #pragma unroll
      for (int ni = 0; ni < 4; ni++) {
        int r = nbase + ni * 16 + ln;
        bb[ni] = *(const bf16x8*)&Bs[r * 128 + ((g ^ ln) << 3)];
      }
      #pragma unroll
      for (int mi = 0; mi < 2; mi++)
        #pragma unroll
        for (int ni = 0; ni < 4; ni++)
          acc[mi][ni] = __builtin_amdgcn_mfma_f32_16x16x32_bf16(a[mi], bb[ni], acc[mi][ni], 0, 0, 0);
    }
    __syncthreads();
  }
  float b1v[4], w2v[4];
  #pragma unroll
  for (int ni = 0; ni < 4; ni++) {
    int col = nbase + ni * 16 + ln;
    b1v[ni] = b1[col]; w2v[ni] = W2[col];
  }
  float s = 0.f;
  #pragma unroll
  for (int mi = 0; mi < 2; mi++) {
    int gm0 = row0 + mbase + mi * 16 + quad * 4;
    #pragma unroll
    for (int r = 0; r < 4; r++) {
      if (gm0 + r < M) {
        #pragma unroll
        for (int ni = 0; ni < 4; ni++)
          s += tanhf(acc[mi][ni][r] + b1v[ni]) * w2v[ni];
      }
    }
  }
  #pragma unroll
  for (int o = 32; o > 0; o >>= 1) s += __shfl_down(s, o);
  if (lane == 0) atomicAdd(&wsum[p0 + pl], s);
}

// ---------------------------------------------------------------------------
// pool: LDS 2-stage segment sum of emb by graph id, 64-feat slice per block.x
// ---------------------------------------------------------------------------
__global__ __launch_bounds__(256) void pool_kernel(
    const unsigned short* __restrict__ emb, const int* __restrict__ gid,
    float* __restrict__ pool, int N, int p0, size_t embstride) {
  __shared__ float acc[BG * 64];
  int pl = blockIdx.z;
  const unsigned short* embp = emb + (size_t)pl * embstride;
  float* poolp = pool + (size_t)(p0 + pl) * BG * HF;
  int f0 = blockIdx.x * 64;
  int lane = threadIdx.x & 63, grp = threadIdx.x >> 6;
  for (int i = threadIdx.x; i < BG * 64; i += 256) acc[i] = 0.f;
  __syncthreads();
  int nb = (int)gridDim.y;
  int chunk = (N + nb - 1) / nb;
  int start = blockIdx.y * chunk;
  int end = min(start + chunk, N);
  int glen = (end - start + 3) >> 2;
  int gstart = start + grp * glen;
  int gend = min(gstart + glen, end);
  for (int n = gstart; n < gend; n++) {
    int g = gid[n];
    float v = b2f(embp[(size_t)n * HF + f0 + lane]);
    atomicAdd(&acc[g * 64 + lane], v);
  }
  __syncthreads();
  for (int i = threadIdx.x; i < BG * 64; i += 256) {
    float v = acc[i];
    if (v != 0.f) {
      int g = i >> 6, f = i & 63;
      atomicAdd(&poolp[g * HF + f0 + f], v);
    }
  }
}

// ---------------------------------------------------------------------------
// final: per-graph count (in-kernel), beta softmax, fuse, logits + pooled out
// ---------------------------------------------------------------------------
__global__ __launch_bounds__(256) void final_kernel(
    const float* __restrict__ pool, const float* __restrict__ wsum,
    const int* __restrict__ gid, const float* __restrict__ clsW,
    const float* __restrict__ clsb, float* __restrict__ out, int N) {
  int b = blockIdx.x;
  int f = threadIdx.x;
  __shared__ int ci[256];
  int cl = 0;
  for (int i = f; i < N; i += 256) cl += (gid[i] == b) ? 1 : 0;
  ci[f] = cl;
  __syncthreads();
  for (int st = 128; st > 0; st >>= 1) {
    if (f < st) ci[f] += ci[f + st];
    __syncthreads();
  }
  float c = fmaxf((float)ci[0], 1.f);
  float wm[PM];
  float mx = -1e30f;
  #pragma unroll
  for (int p = 0; p < PM; p++) { wm[p] = wsum[p] / (float)N; mx = fmaxf(mx, wm[p]); }
  float es = 0.f, e[PM];
  #pragma unroll
  for (int p = 0; p < PM; p++) { e[p] = expf(wm[p] - mx); es += e[p]; }
  float v = 0.f;
  #pragma unroll
  for (int p = 0; p < PM; p++)
    v += (e[p] / es) * pool[((size_t)p * BG + b) * HF + f];
  v /= c;
  out[256 + (size_t)b * HF + f] = v;
  __shared__ float sm[256];
  sm[f] = v * clsW[f * 2 + 0];
  __syncthreads();
  for (int st = 128; st > 0; st >>= 1) {
    if (f < st) sm[f] += sm[f + st];
    __syncthreads();
  }
  float l0 = sm[0];
  __syncthreads();
  sm[f] = v * clsW[f * 2 + 1];
  __syncthreads();
  for (int st = 128; st > 0; st >>= 1) {
    if (f < st) sm[f] += sm[f + st];
    __syncthreads();
  }
  if (f == 0) {
    out[b * 2 + 0] = l0 + clsb[0];
    out[b * 2 + 1] = sm[0] + clsb[1];
  }
}

// ---------------------------------------------------------------------------
extern "C" void kernel_launch(void* const* d_in, const int* in_sizes, int n_in,
                              void* d_out, int out_size, void* d_ws, size_t ws_size,
                              hipStream_t stream) {
  const float* h      = (const float*)d_in[0];
  const float* Wg     = (const float*)d_in[1];
  const float* attn_l = (const float*)d_in[2];
  const float* attn_r = (const float*)d_in[3];
  const float* gatb   = (const float*)d_in[4];
  const float* semW1  = (const float*)d_in[5];
  const float* semb1  = (const float*)d_in[6];
  const float* semW2  = (const float*)d_in[7];
  const float* clsW   = (const float*)d_in[8];
  const float* clsb   = (const float*)d_in[9];
  const int*   src    = (const int*)d_in[10];
  const int*   dst    = (const int*)d_in[11];
  const int*   gid    = (const int*)d_in[12];
  float* out = (float*)d_out;

  // try batched layout (per-p big buffers); fall back to looped if ws too small
  auto layout_size = [](int PMg) -> size_t {
    size_t o = 0;
    auto alloc = [&](size_t bytes) { o += (bytes + 255) & ~(size_t)255; };
    alloc((size_t)NN * INF_ * 2);              // h_b
    alloc((size_t)PMg * NN * HF * 2);          // hp_b
    alloc((size_t)PMg * NN * HF * 2);          // emb_b
    alloc((size_t)PM * HF * INF_ * 2);         // Wb_t
    alloc((size_t)HS * HF * 2);                // W1_t
    alloc((size_t)PM * INF_ * NH * 4);         // wl
    alloc((size_t)PM * INF_ * NH * 4);         // wr
    alloc((size_t)PMg * NN * NH * 4);          // el
    alloc((size_t)PMg * NN * NH * 4);          // er
    alloc((size_t)PM * NB2 * BCAP * 4);        // bdata
    alloc((size_t)PM * NB2 * 4);               // gcnt
    alloc((size_t)PM * (NN + 1) * 4);          // off
    alloc((size_t)PM * EE * 2);                // csr
    alloc((size_t)PM * BG * HF * 4);           // pool
    alloc(PM * 4);                             // wsum
    return o;
  };
  int PMg = (layout_size(4) <= ws_size) ? 4 : 1;

  char* ws = (char*)d_ws;
  size_t o = 0;
  auto alloc = [&](size_t bytes) { size_t r = o; o += (bytes + 255) & ~(size_t)255; return r; };
  unsigned short* h_b   = (unsigned short*)(ws + alloc((size_t)NN * INF_ * 2));
  unsigned short* hp_b  = (unsigned short*)(ws + alloc((size_t)PMg * NN * HF * 2));
  unsigned short* emb_b = (unsigned short*)(ws + alloc((size_t)PMg * NN * HF * 2));
  unsigned short* Wb_t  = (unsigned short*)(ws + alloc((size_t)PM * HF * INF_ * 2));
  unsigned short* W1_t  = (unsigned short*)(ws + alloc((size_t)HS * HF * 2));
  float* wl    = (float*)(ws + alloc((size_t)PM * INF_ * NH * 4));
  float* wr    = (float*)(ws + alloc((size_t)PM * INF_ * NH * 4));
  float* el    = (float*)(ws + alloc((size_t)PMg * NN * NH * 4));
  float* er    = (float*)(ws + alloc((size_t)PMg * NN * NH * 4));
  unsigned* bdata = (unsigned*)(ws + alloc((size_t)PM * NB2 * BCAP * 4));
  int*   gcnt  = (int*)(ws + alloc((size_t)PM * NB2 * 4));
  int*   off   = (int*)(ws + alloc((size_t)PM * (NN + 1) * 4));
  unsigned short* csr = (unsigned short*)(ws + alloc((size_t)PM * EE * 2));
  float* pool  = (float*)(ws + alloc((size_t)PM * BG * HF * 4));
  float* wsum  = (float*)(ws + alloc(PM * 4));

  const size_t hpS  = (PMg == 4) ? (size_t)NN * HF : 0;
  const size_t embS = hpS;
  const size_t elS  = (PMg == 4) ? (size_t)NN * NH : 0;

  prep_kernel<<<128 + 1 + 6250 + 512 + 128 + 16, 256, 0, stream>>>(
      h, Wg, semW1, attn_l, attn_r, h_b, Wb_t, W1_t, wl, wr, pool, gcnt, wsum);
  bucket_kernel<<<dim3((EE + BCH - 1) / BCH, PM), 256, 0, stream>>>(src, dst, bdata, gcnt);
  csrify_kernel<<<dim3(NB2, PM), 256, 0, stream>>>(bdata, gcnt, off, csr);

  if (PMg == 4) {
    gemm1_kernel<<<dim3((NN + 63) / 64, 2, 4), 256, 0, stream>>>(h_b, Wb_t, hp_b, NN, 0, hpS);
    elr_kernel<<<dim3((NN + 255) / 256, 4), 256, 0, stream>>>(h, wl, wr, el, er, NN, 0, elS);
    agg_kernel<<<dim3((NN + 3) / 4, 4), 256, 0, stream>>>(
        hp_b, el, er, csr, off, gatb, emb_b, NN, 0, hpS, elS, embS);
    gemm2_kernel<<<dim3((NN + 63) / 64, 4), 256, 0, stream>>>(
        emb_b, W1_t, semb1, semW2, wsum, NN, 0, embS);
    pool_kernel<<<dim3(4, 64, 4), 256, 0, stream>>>(emb_b, gid, pool, NN, 0, embS);
  } else {
    for (int p = 0; p < PM; p++) {
      gemm1_kernel<<<dim3((NN + 63) / 64, 2, 1), 256, 0, stream>>>(h_b, Wb_t, hp_b, NN, p, 0);
      elr_kernel<<<dim3((NN + 255) / 256, 1), 256, 0, stream>>>(h, wl, wr, el, er, NN, p, 0);
      agg_kernel<<<dim3((NN + 3) / 4, 1), 256, 0, stream>>>(
          hp_b, el, er, csr, off, gatb, emb_b, NN, p, 0, 0, 0);
      gemm2_kernel<<<dim3((NN + 63) / 64, 1), 256, 0, stream>>>(
          emb_b, W1_t, semb1, semW2, wsum, NN, p, 0);
      pool_kernel<<<dim3(4, 64, 1), 256, 0, stream>>>(emb_b, gid, pool, NN, p, 0);
    }
  }

  final_kernel<<<BG, 256, 0, stream>>>(pool, wsum, gid, clsW, clsb, out, NN);
}